// Round 9
// baseline (352.353 us; speedup 1.0000x reference)
//
#include <hip/hip_runtime.h>
#include <hip/hip_bf16.h>
#include <float.h>
#include <math.h>

#define N_NODES 50000
#define N_EDGES 500000
#define D 128
#define ED 10
#define EPS_PNA 1e-5f
#define SCAN_NTILES 49     // ceil(50000 / 1024)
#define XGEMM_BLOCKS 391   // ceil(50000 / 128)
#define HIST_BLOCKS 1954   // ceil(500000 / 256)

typedef __hip_bfloat16 bf16;
typedef unsigned short ushort;
typedef unsigned int uint;
typedef __attribute__((ext_vector_type(8))) short short8;   // 8 bf16 (4 VGPRs)
typedef __attribute__((ext_vector_type(4))) float f32x4;    // MFMA C/D

__device__ __forceinline__ ushort f2bf(float f) {
    __hip_bfloat16 h = __float2bfloat16(f);
    return *reinterpret_cast<ushort*>(&h);
}
__device__ __forceinline__ float bf2f(ushort u) {
    return __uint_as_float(((uint)u) << 16);
}

// ---------------- K2a: per-tile reduce (sum + logsum), 1024 nodes/tile ----------------
__global__ __launch_bounds__(256) void k_scanA(const int* __restrict__ cnt,
                                               int* __restrict__ bsum,
                                               float* __restrict__ blog) {
    const int t = threadIdx.x;
    const int base = blockIdx.x * 1024;
    int s = 0; float ls = 0.f;
    #pragma unroll
    for (int k = 0; k < 4; ++k) {
        const int idx = base + t + k * 256;
        if (idx < N_NODES) {
            const int c = cnt[idx];
            s += c;
            ls += logf((float)c + 1.0f);
        }
    }
    #pragma unroll
    for (int off = 32; off > 0; off >>= 1) {
        s += __shfl_down(s, off, 64);
        ls += __shfl_down(ls, off, 64);
    }
    __shared__ int ws[4]; __shared__ float wl[4];
    const int wv = t >> 6, l = t & 63;
    if (l == 0) { ws[wv] = s; wl[wv] = ls; }
    __syncthreads();
    if (t == 0) {
        bsum[blockIdx.x] = ws[0] + ws[1] + ws[2] + ws[3];
        blog[blockIdx.x] = wl[0] + wl[1] + wl[2] + wl[3];
    }
}

// ---------------- K2c: per-tile scan; each block re-scans the 49 tile sums locally ----
__global__ __launch_bounds__(256) void k_scanC(const int* __restrict__ cnt,
                                               const int* __restrict__ bsum,
                                               const float* __restrict__ blog,
                                               int* __restrict__ rowstart,
                                               int* __restrict__ cursor,
                                               float* __restrict__ avglog) {
    const int t = threadIdx.x, lane = t & 63, wv = t >> 6;
    __shared__ int sboff;
    if (t < 64) {
        const int v = (t < SCAN_NTILES) ? bsum[t] : 0;
        int s = v;
        #pragma unroll
        for (int off = 1; off < 64; off <<= 1) {
            const int u = __shfl_up(s, off, 64);
            if (t >= off) s += u;
        }
        if (t == blockIdx.x) sboff = s - v;                    // exclusive prefix
        if (blockIdx.x == 0 && t == SCAN_NTILES - 1)
            rowstart[N_NODES] = s;                             // grand total
        if (blockIdx.x == 0) {
            float lg = (t < SCAN_NTILES) ? blog[t] : 0.f;
            #pragma unroll
            for (int off = 32; off > 0; off >>= 1) lg += __shfl_down(lg, off, 64);
            if (t == 0) avglog[0] = lg * (1.0f / (float)N_NODES);
        }
    }
    const int base = blockIdx.x * 1024;
    int c[4]; int ts = 0;
    #pragma unroll
    for (int k = 0; k < 4; ++k) {
        const int idx = base + t * 4 + k;
        c[k] = (idx < N_NODES) ? cnt[idx] : 0;
        ts += c[k];
    }
    int s = ts;
    #pragma unroll
    for (int off = 1; off < 64; off <<= 1) {
        const int u = __shfl_up(s, off, 64);
        if (lane >= off) s += u;
    }
    __shared__ int wtot[4], woff[4];
    if (lane == 63) wtot[wv] = s;
    __syncthreads();
    if (t == 0) {
        int r = 0;
        #pragma unroll
        for (int i = 0; i < 4; ++i) { woff[i] = r; r += wtot[i]; }
    }
    __syncthreads();
    int excl = sboff + woff[wv] + (s - ts);
    #pragma unroll
    for (int k = 0; k < 4; ++k) {
        const int idx = base + t * 4 + k;
        if (idx < N_NODES) { rowstart[idx] = excl; cursor[idx] = excl; }
        excl += c[k];
    }
}

// ---------------- K3: bucket edges into CSR order as 48B self-contained records ----
__global__ void k_scatter(const int* __restrict__ ei, const float* __restrict__ eattr,
                          int* __restrict__ cursor, uint4* __restrict__ csr_rec) {
    int e = blockIdx.x * blockDim.x + threadIdx.x;
    if (e < N_EDGES) {
        const int dst = ei[N_EDGES + e];
        const int src = ei[e];
        const float2* ea2 = (const float2*)(eattr + (size_t)e * ED);
        const float2 a0 = ea2[0], a1 = ea2[1], a2 = ea2[2], a3 = ea2[3], a4 = ea2[4];
        const int pos = atomicAdd(&cursor[dst], 1);
        uint4* o = csr_rec + (size_t)pos * 3;
        o[0] = make_uint4(__float_as_uint(a0.x), __float_as_uint(a0.y),
                          __float_as_uint(a1.x), __float_as_uint(a1.y));
        o[1] = make_uint4(__float_as_uint(a2.x), __float_as_uint(a2.y),
                          __float_as_uint(a3.x), __float_as_uint(a3.y));
        o[2] = make_uint4(__float_as_uint(a4.x), __float_as_uint(a4.y), (uint)src, 0u);
    }
}

// ---------------- K_wprep: fused weight-prep + cnt-init (role-dispatched by blockIdx) ----
// fold role now reads Wlin directly from global (coalesced per-m across the 128
// j-threads, L2-hot after the first block) -- no 64KB LDS stage, no barrier.
__global__ __launch_bounds__(256) void k_wprep(
    const float* __restrict__ Wee, const float* __restrict__ bee,
    const float* __restrict__ Wpre, const float* __restrict__ bpre,
    const float* __restrict__ Wpost, const float* __restrict__ bpost,
    const float* __restrict__ Wlin, const float* __restrict__ blin,
    float* __restrict__ W4, float* __restrict__ bp,
    ushort* __restrict__ WxT,     // [384][128]
    ushort* __restrict__ WaT,     // [384][512]
    float* __restrict__ b_comb,
    int* __restrict__ cnt)
{
    __shared__ float smem[(ED + 1) * D];   // small-role staging only
    const int t = threadIdx.x;
    const int bx = blockIdx.x;

    if (bx < 104) {
        const int j = t & 127, rp = t >> 7;
        const int kr0 = bx * 16 + rp * 8;
        for (int r = 0; r < 8; ++r) {
            const int kr = kr0 + r;
            const float* wrow = Wpost + (size_t)kr * 128;
            float acc = 0.f;
            #pragma unroll 8
            for (int m = 0; m < 128; ++m) acc += wrow[m] * Wlin[m * 128 + j];
            const ushort v = f2bf(acc);
            if (kr < 128)       WxT[(256 + j) * 128 + kr] = v;
            else if (kr < 640)  WaT[(size_t)j * 512 + (kr - 128)] = v;
            else if (kr < 1152) WaT[(size_t)(128 + j) * 512 + (kr - 640)] = v;
            else                WaT[(size_t)(256 + j) * 512 + (kr - 1152)] = v;
        }
        if (bx == 0 && t < 128) {
            float acc = 0.f;
            #pragma unroll 8
            for (int m = 0; m < 128; ++m) acc += bpost[m] * Wlin[m * 128 + t];
            b_comb[t] = acc + blin[t];
        }
    } else if (bx == 104) {
        float* wee_s = smem;                 // ED*D
        float* bee_s = smem + ED * D;        // D
        for (int i = t; i < ED * D; i += 256) wee_s[i] = Wee[i];
        if (t < 128) bee_s[t] = bee[t];
        __syncthreads();
        if (t < 128) {
            float acc[ED];
            #pragma unroll
            for (int r = 0; r < ED; ++r) acc[r] = 0.f;
            float bacc = 0.f;
            for (int k = 0; k < D; ++k) {
                const float w3 = Wpre[(size_t)(2 * D + k) * D + t];
                #pragma unroll
                for (int r = 0; r < ED; ++r) acc[r] += wee_s[r * D + k] * w3;
                bacc += bee_s[k] * w3;
            }
            #pragma unroll
            for (int r = 0; r < ED; ++r) W4[r * D + t] = acc[r];
            bp[t] = bpre[t] + bacc;
        }
    } else if (bx < 121) {
        const int slice = (bx < 113) ? 0 : 1;
        const int id = (bx - (slice ? 113 : 105)) * 256 + t;   // 0..2047
        const float* src = Wpre + (size_t)slice * 128 * 128;
        ushort* dst = WxT + (size_t)slice * 128 * 128;
        const int col = id & 127;
        const int k0 = (id >> 7) * 8;
        ushort tmp[8];
        #pragma unroll
        for (int r = 0; r < 8; ++r) tmp[r] = f2bf(src[(size_t)(k0 + r) * 128 + col]);
        *(uint4*)(dst + (size_t)col * 128 + k0) = *(uint4*)tmp;
    } else {
        const int i = (bx - 121) * 256 + t;
        if (i < N_NODES) cnt[i] = 0;
    }
}

// ---------------- K_hx: fused hist + xgemm (both depend only on k_wprep) -------------
__global__ __launch_bounds__(256) void k_hx(
    const int* __restrict__ ei, int* __restrict__ cnt,
    const float* __restrict__ x, const ushort* __restrict__ WxT,
    const float* __restrict__ b_comb,
    ushort* __restrict__ Y1b, ushort* __restrict__ Y2b, float* __restrict__ out)
{
    const int t = threadIdx.x;
    if (blockIdx.x >= XGEMM_BLOCKS) {
        const int e = (blockIdx.x - XGEMM_BLOCKS) * 256 + t;
        if (e < N_EDGES) atomicAdd(&cnt[ei[N_EDGES + e]], 1);
        return;
    }

    __shared__ __align__(16) ushort Alds[128 * 136];
    __shared__ __align__(16) ushort Hlds[128 * 136];
    const int nb = blockIdx.x * 128;

    #pragma unroll
    for (int g = 0; g < 8; ++g) {
        const int idx = t + g * 256;
        const int row = idx >> 4, kk = (idx & 15) * 8;
        const int node = nb + row;
        uint4 v = make_uint4(0u, 0u, 0u, 0u);
        if (node < N_NODES) {
            const float4 f0 = *(const float4*)(x + (size_t)node * 128 + kk);
            const float4 f1 = *(const float4*)(x + (size_t)node * 128 + kk + 4);
            __hip_bfloat162 p0 = __float22bfloat162_rn(make_float2(f0.x, f0.y));
            __hip_bfloat162 p1 = __float22bfloat162_rn(make_float2(f0.z, f0.w));
            __hip_bfloat162 p2 = __float22bfloat162_rn(make_float2(f1.x, f1.y));
            __hip_bfloat162 p3 = __float22bfloat162_rn(make_float2(f1.z, f1.w));
            v.x = *(uint*)&p0; v.y = *(uint*)&p1; v.z = *(uint*)&p2; v.w = *(uint*)&p3;
        }
        *(uint4*)&Hlds[row * 136 + kk] = v;
    }

    const int w = t >> 6, l = t & 63;
    const int wr = w >> 1, wc = w & 1;
    const int quad = l >> 4, lr = l & 15;

    for (int sy = 0; sy < 3; ++sy) {
        __syncthreads();
        #pragma unroll
        for (int g = 0; g < 8; ++g) {
            const int idx = t + g * 256;
            const int row = idx >> 4, kk = (idx & 15) * 8;
            *(uint4*)&Alds[row * 136 + kk] =
                *(const uint4*)(WxT + ((size_t)sy * 128 + row) * 128 + kk);
        }
        __syncthreads();

        f32x4 acc[4][4];
        #pragma unroll
        for (int i = 0; i < 4; ++i)
            #pragma unroll
            for (int j = 0; j < 4; ++j) acc[i][j] = (f32x4){0.f, 0.f, 0.f, 0.f};

        #pragma unroll
        for (int s = 0; s < 4; ++s) {
            short8 av[4], bv[4];
            #pragma unroll
            for (int i = 0; i < 4; ++i)
                av[i] = *(const short8*)&Alds[(wr * 64 + i * 16 + lr) * 136 + s * 32 + quad * 8];
            #pragma unroll
            for (int j = 0; j < 4; ++j)
                bv[j] = *(const short8*)&Hlds[(wc * 64 + j * 16 + lr) * 136 + s * 32 + quad * 8];
            #pragma unroll
            for (int i = 0; i < 4; ++i)
                #pragma unroll
                for (int j = 0; j < 4; ++j)
                    acc[i][j] = __builtin_amdgcn_mfma_f32_16x16x32_bf16(av[i], bv[j], acc[i][j], 0, 0, 0);
        }

        #pragma unroll
        for (int i = 0; i < 4; ++i) {
            const int col = wr * 64 + i * 16 + quad * 4;
            #pragma unroll
            for (int j = 0; j < 4; ++j) {
                const int node = nb + wc * 64 + j * 16 + lr;
                if (node < N_NODES) {
                    const f32x4 v = acc[i][j];
                    if (sy == 2) {
                        *(float4*)(out + (size_t)node * 128 + col) =
                            make_float4(v.x + b_comb[col],     v.y + b_comb[col + 1],
                                        v.z + b_comb[col + 2], v.w + b_comb[col + 3]);
                    } else {
                        ushort* dst = (sy == 0) ? Y1b : Y2b;
                        ushort pk[4];
                        pk[0] = f2bf(v.x); pk[1] = f2bf(v.y);
                        pk[2] = f2bf(v.z); pk[3] = f2bf(v.w);
                        *(uint2*)(dst + (size_t)node * 128 + col) = *(uint2*)pk;
                    }
                }
            }
        }
    }
}

// ---------------- K8: CSR pull aggregation -> agg bf16 [N][512] ----------------
// Round-8 proven structure (scalar records + reg W4, no LDS). UNCHANGED.
__global__ __launch_bounds__(256) void k_pull(
    const uint4* __restrict__ csr_rec, const float* __restrict__ W4,
    const float* __restrict__ bp, const ushort* __restrict__ Y1b,
    const ushort* __restrict__ Y2b,
    const int* __restrict__ rowstart,
    ushort* __restrict__ aggB)
{
    const int t = threadIdx.x;
    const int wv = t >> 6, l = t & 63;
    const int n = blockIdx.x * 4 + wv;

    // per-lane W4 slice (coalesced 512B/wave loads, L2-hot)
    float2 w4[ED];
    #pragma unroll
    for (int r = 0; r < ED; ++r)
        w4[r] = *(const float2*)(W4 + r * D + 2 * l);

    const int r0 = __builtin_amdgcn_readfirstlane(rowstart[n]);
    const int r1 = __builtin_amdgcn_readfirstlane(rowstart[n + 1]);
    const int d = r1 - r0;

    float s0 = 0.f, s1 = 0.f, ss0 = 0.f, ss1 = 0.f;
    float mx0 = -FLT_MAX, mx1 = -FLT_MAX, mn0 = FLT_MAX, mn1 = FLT_MAX;
    const __hip_bfloat162* Y2p = (const __hip_bfloat162*)Y2b;

    uint4 ra, rb, rc;
    if (d > 0) {
        const uint4* rp = csr_rec + (size_t)r0 * 3;
        ra = rp[0]; rb = rp[1]; rc = rp[2];
    }
    for (int i = r0; i < r1; ++i) {
        const int inext = (i + 1 < r1) ? (i + 1) : i;   // uniform, branchless clamp
        const uint4* rp = csr_rec + (size_t)inext * 3;
        const uint4 na = rp[0], nb4 = rp[1], nc = rp[2];

        const int src = (int)rc.z;                       // uniform -> scalar row base
        const float2 y2 = __bfloat1622float2(Y2p[(size_t)src * 64 + l]);

        float ea[10];
        ea[0] = __uint_as_float(ra.x); ea[1] = __uint_as_float(ra.y);
        ea[2] = __uint_as_float(ra.z); ea[3] = __uint_as_float(ra.w);
        ea[4] = __uint_as_float(rb.x); ea[5] = __uint_as_float(rb.y);
        ea[6] = __uint_as_float(rb.z); ea[7] = __uint_as_float(rb.w);
        ea[8] = __uint_as_float(rc.x); ea[9] = __uint_as_float(rc.y);

        float q0 = 0.f, q1 = 0.f;
        #pragma unroll
        for (int r = 0; r < ED; ++r) {
            q0 += ea[r] * w4[r].x;
            q1 += ea[r] * w4[r].y;
        }
        const float z0 = y2.x + q0, z1 = y2.y + q1;
        s0 += z0; s1 += z1;
        ss0 += z0 * z0; ss1 += z1 * z1;
        mx0 = fmaxf(mx0, z0); mx1 = fmaxf(mx1, z1);
        mn0 = fminf(mn0, z0); mn1 = fminf(mn1, z1);

        ra = na; rb = nb4; rc = nc;
    }

    const float2 bpw = ((const float2*)bp)[l];
    const float2 y1 = __bfloat1622float2(((const __hip_bfloat162*)Y1b)[(size_t)n * 64 + l]);
    float mean0, mean1, vmx0, vmx1, vmn0, vmn1, st0, st1;
    if (d > 0) {
        const float inv = 1.f / (float)d;
        const float mz0 = s0 * inv, mz1 = s1 * inv;
        const float c0 = y1.x + bpw.x, c1 = y1.y + bpw.y;
        mean0 = mz0 + c0; mean1 = mz1 + c1;
        st0 = sqrtf(fmaxf(ss0 * inv - mz0 * mz0, 0.f) + EPS_PNA);
        st1 = sqrtf(fmaxf(ss1 * inv - mz1 * mz1, 0.f) + EPS_PNA);
        vmx0 = mx0 + c0; vmx1 = mx1 + c1;
        vmn0 = mn0 + c0; vmn1 = mn1 + c1;
    } else {
        mean0 = mean1 = 0.f;
        vmx0 = vmx1 = vmn0 = vmn1 = 0.f;
        st0 = st1 = sqrtf(EPS_PNA);
    }
    __hip_bfloat162* aggv = (__hip_bfloat162*)aggB;
    const size_t b0 = (size_t)n * 256;
    aggv[b0 + l]       = __float22bfloat162_rn(make_float2(mean0, mean1));
    aggv[b0 + 64 + l]  = __float22bfloat162_rn(make_float2(vmx0, vmx1));
    aggv[b0 + 128 + l] = __float22bfloat162_rn(make_float2(vmn0, vmn1));
    aggv[b0 + 192 + l] = __float22bfloat162_rn(make_float2(st0, st1));
}

// ---------------- K9: MFMA agg-GEMM v3 -------------------------------------------
// A-fragments (WaT, 384KB, shared by ALL blocks -> L2-resident) loaded DIRECTLY
// from global into registers -- no A LDS staging. Only H (this block's aggB tile)
// stays in LDS. LDS 65KB -> ~10KB per block: occupancy cap moves to VGPR,
// ~2x more resident waves to cover the stage latency.
__global__ __launch_bounds__(256) void k_agg(
    const ushort* __restrict__ aggB,  // [N][512] bf16
    const ushort* __restrict__ WaT,   // [384][512] bf16
    const int* __restrict__ cnt, const float* __restrict__ avglog,
    float* __restrict__ out)
{
    __shared__ __align__(16) ushort Hlds[64 * 72];       //  9.2 KB
    __shared__ float r1s[64], r2s[64];

    const int t = threadIdx.x;
    const int nb = blockIdx.x * 64;
    if (t < 64) {
        const int node = nb + t;
        float deg = 1.f;
        if (node < N_NODES) deg = fmaxf((float)cnt[node], 1.f);
        const float sl = logf(deg + 1.f);
        const float al = avglog[0];
        r1s[t] = sl / al;
        r2s[t] = al / sl;
    }

    const int w = t >> 6, l = t & 63;
    const int wr = w >> 1, wc = w & 1;   // wr: col half (64), wc: node half (32)
    const int quad = l >> 4, lr = l & 15;

    // per-lane WaT base: row (wr*64 + lr), col chunk quad*8
    const ushort* wbase = WaT + (size_t)(wr * 64 + lr) * 512 + quad * 8;

    f32x4 acc[3][4][2];
    #pragma unroll
    for (int sl = 0; sl < 3; ++sl)
        #pragma unroll
        for (int i = 0; i < 4; ++i)
            #pragma unroll
            for (int j = 0; j < 2; ++j) acc[sl][i][j] = (f32x4){0.f, 0.f, 0.f, 0.f};

    for (int kc = 0; kc < 8; ++kc) {
        const int k0 = kc * 64;
        __syncthreads();                       // prior epoch's Hlds reads done
        #pragma unroll
        for (int g = 0; g < 2; ++g) {          // H: 64 rows x 64 k -> LDS
            const int idx = t + g * 256;
            const int row = idx >> 3, kk = (idx & 7) * 8;
            const int node = nb + row;
            uint4 v = make_uint4(0u, 0u, 0u, 0u);
            if (node < N_NODES)
                v = *(const uint4*)(aggB + (size_t)node * 512 + k0 + kk);
            *(uint4*)&Hlds[row * 72 + kk] = v;
        }
        __syncthreads();                       // H visible
        #pragma unroll
        for (int sl = 0; sl < 3; ++sl) {
            const ushort* wsl = wbase + (size_t)sl * 128 * 512 + k0;
            #pragma unroll
            for (int s = 0; s < 2; ++s) {
                short8 av[4], bv[2];
                #pragma unroll
                for (int i = 0; i < 4; ++i)     // A direct from global (L2-hot)
                    av[i] = *(const short8*)(wsl + (size_t)i * 16 * 512 + s * 32);
                #pragma unroll
                for (int j = 0; j < 2; ++j)
                    bv[j] = *(const short8*)&Hlds[(wc * 32 + j * 16 + lr) * 72 + s * 32 + quad * 8];
                #pragma unroll
                for (int i = 0; i < 4; ++i)
                    #pragma unroll
                    for (int j = 0; j < 2; ++j)
                        acc[sl][i][j] = __builtin_amdgcn_mfma_f32_16x16x32_bf16(av[i], bv[j], acc[sl][i][j], 0, 0, 0);
            }
        }
    }

    #pragma unroll
    for (int i = 0; i < 4; ++i) {
        const int col = wr * 64 + i * 16 + quad * 4;
        #pragma unroll
        for (int j = 0; j < 2; ++j) {
            const int node = nb + wc * 32 + j * 16 + lr;
            if (node < N_NODES) {
                const int nl = wc * 32 + j * 16 + lr;
                const float r1 = r1s[nl], r2 = r2s[nl];
                float* op = out + (size_t)node * 128 + col;
                const float4 cur = *(const float4*)op;
                const f32x4 a0 = acc[0][i][j];
                const f32x4 a1 = acc[1][i][j];
                const f32x4 a2 = acc[2][i][j];
                *(float4*)op = make_float4(
                    cur.x + a0.x + r1 * a1.x + r2 * a2.x,
                    cur.y + a0.y + r1 * a1.y + r2 * a2.y,
                    cur.z + a0.z + r1 * a1.z + r2 * a2.z,
                    cur.w + a0.w + r1 * a1.w + r2 * a2.w);
            }
        }
    }
}

extern "C" void kernel_launch(void* const* d_in, const int* in_sizes, int n_in,
                              void* d_out, int out_size, void* d_ws, size_t ws_size,
                              hipStream_t stream) {
    const float* x     = (const float*)d_in[0];
    const float* eattr = (const float*)d_in[1];
    const float* Wee   = (const float*)d_in[2];
    const float* bee   = (const float*)d_in[3];
    const float* Wpre  = (const float*)d_in[4];
    const float* bpre  = (const float*)d_in[5];
    const float* Wpost = (const float*)d_in[6];
    const float* bpost = (const float*)d_in[7];
    const float* Wlin  = (const float*)d_in[8];
    const float* blin  = (const float*)d_in[9];
    const int*   ei    = (const int*)d_in[10];
    float* out = (float*)d_out;

    // workspace layout (~101.9 MB; ws_size >= 102.6 MB proven previously)
    ushort* aggB = (ushort*)d_ws;                         // N*512 bf16 (51.2 MB)
    ushort* Y1b  = aggB + (size_t)N_NODES * 512;          // N*128 bf16 (12.8 MB)
    ushort* Y2b  = Y1b  + (size_t)N_NODES * 128;          // N*128 bf16 (12.8 MB)
    ushort* WxT  = Y2b  + (size_t)N_NODES * 128;          // 384*128 bf16
    ushort* WaT  = WxT + 384 * 128;                       // 384*512 bf16
    float*  W4   = (float*)(WaT + 384 * 512);             // ED*D fp32
    float*  bp   = W4 + ED * D;                           // 128
    float*  b_comb = bp + D;                              // 128
    float*  avglog = b_comb + D;                          // 1 (+3 pad)
    int*   cnt      = (int*)(avglog + 4);                 // 50000
    int*   rowstart = cnt + N_NODES;                      // 50001 (+3 pad)
    int*   cursor   = rowstart + N_NODES + 4;             // 50000
    uint4* csr_rec  = (uint4*)(cursor + N_NODES);         // E*48B (24.0 MB), 16B-aligned
    int*   bsum     = (int*)(csr_rec + (size_t)N_EDGES * 3);  // 49
    float* blog     = (float*)(bsum + 64);                // 49

    k_wprep<<<317, 256, 0, stream>>>(Wee, bee, Wpre, bpre, Wpost, bpost, Wlin, blin,
                                     W4, bp, WxT, WaT, b_comb, cnt);
    k_hx<<<XGEMM_BLOCKS + HIST_BLOCKS, 256, 0, stream>>>(ei, cnt, x, WxT, b_comb,
                                                         Y1b, Y2b, out);
    k_scanA<<<SCAN_NTILES, 256, 0, stream>>>(cnt, bsum, blog);
    k_scanC<<<SCAN_NTILES, 256, 0, stream>>>(cnt, bsum, blog, rowstart, cursor, avglog);
    k_scatter<<<(N_EDGES + 255) / 256, 256, 0, stream>>>(ei, eattr, cursor, csr_rec);
    k_pull<<<N_NODES / 4, 256, 0, stream>>>(csr_rec, W4, bp, Y1b, Y2b,
                                            rowstart, aggB);
    k_agg<<<(N_NODES + 63) / 64, 256, 0, stream>>>(aggB, WaT, cnt, avglog, out);
}

// Round 10
// 280.306 us; speedup vs baseline: 1.2570x; 1.2570x over previous
//
#include <hip/hip_runtime.h>
#include <hip/hip_bf16.h>
#include <float.h>
#include <math.h>

#define N_NODES 50000
#define N_EDGES 500000
#define D 128
#define ED 10
#define EPS_PNA 1e-5f
#define SCAN_NTILES 49     // ceil(50000 / 1024)
#define XGEMM_BLOCKS 391   // ceil(50000 / 128)
#define HIST_BLOCKS 1954   // ceil(500000 / 256)

typedef __hip_bfloat16 bf16;
typedef unsigned short ushort;
typedef unsigned int uint;
typedef __attribute__((ext_vector_type(8))) short short8;   // 8 bf16 (4 VGPRs)
typedef __attribute__((ext_vector_type(4))) float f32x4;    // MFMA C/D

__device__ __forceinline__ ushort f2bf(float f) {
    __hip_bfloat16 h = __float2bfloat16(f);
    return *reinterpret_cast<ushort*>(&h);
}
__device__ __forceinline__ float bf2f(ushort u) {
    return __uint_as_float(((uint)u) << 16);
}
__device__ __forceinline__ uint packbf2(float a, float b) {
    __hip_bfloat162 p = __float22bfloat162_rn(make_float2(a, b));
    return *reinterpret_cast<uint*>(&p);
}

// ---------------- K2a: per-tile reduce (sum + logsum), 1024 nodes/tile ----------------
__global__ __launch_bounds__(256) void k_scanA(const int* __restrict__ cnt,
                                               int* __restrict__ bsum,
                                               float* __restrict__ blog) {
    const int t = threadIdx.x;
    const int base = blockIdx.x * 1024;
    int s = 0; float ls = 0.f;
    #pragma unroll
    for (int k = 0; k < 4; ++k) {
        const int idx = base + t + k * 256;
        if (idx < N_NODES) {
            const int c = cnt[idx];
            s += c;
            ls += logf((float)c + 1.0f);
        }
    }
    #pragma unroll
    for (int off = 32; off > 0; off >>= 1) {
        s += __shfl_down(s, off, 64);
        ls += __shfl_down(ls, off, 64);
    }
    __shared__ int ws[4]; __shared__ float wl[4];
    const int wv = t >> 6, l = t & 63;
    if (l == 0) { ws[wv] = s; wl[wv] = ls; }
    __syncthreads();
    if (t == 0) {
        bsum[blockIdx.x] = ws[0] + ws[1] + ws[2] + ws[3];
        blog[blockIdx.x] = wl[0] + wl[1] + wl[2] + wl[3];
    }
}

// ---------------- K2c: per-tile scan; each block re-scans the 49 tile sums locally ----
__global__ __launch_bounds__(256) void k_scanC(const int* __restrict__ cnt,
                                               const int* __restrict__ bsum,
                                               const float* __restrict__ blog,
                                               int* __restrict__ rowstart,
                                               int* __restrict__ cursor,
                                               float* __restrict__ avglog) {
    const int t = threadIdx.x, lane = t & 63, wv = t >> 6;
    __shared__ int sboff;
    if (t < 64) {
        const int v = (t < SCAN_NTILES) ? bsum[t] : 0;
        int s = v;
        #pragma unroll
        for (int off = 1; off < 64; off <<= 1) {
            const int u = __shfl_up(s, off, 64);
            if (t >= off) s += u;
        }
        if (t == blockIdx.x) sboff = s - v;                    // exclusive prefix
        if (blockIdx.x == 0 && t == SCAN_NTILES - 1)
            rowstart[N_NODES] = s;                             // grand total
        if (blockIdx.x == 0) {
            float lg = (t < SCAN_NTILES) ? blog[t] : 0.f;
            #pragma unroll
            for (int off = 32; off > 0; off >>= 1) lg += __shfl_down(lg, off, 64);
            if (t == 0) avglog[0] = lg * (1.0f / (float)N_NODES);
        }
    }
    const int base = blockIdx.x * 1024;
    int c[4]; int ts = 0;
    #pragma unroll
    for (int k = 0; k < 4; ++k) {
        const int idx = base + t * 4 + k;
        c[k] = (idx < N_NODES) ? cnt[idx] : 0;
        ts += c[k];
    }
    int s = ts;
    #pragma unroll
    for (int off = 1; off < 64; off <<= 1) {
        const int u = __shfl_up(s, off, 64);
        if (lane >= off) s += u;
    }
    __shared__ int wtot[4], woff[4];
    if (lane == 63) wtot[wv] = s;
    __syncthreads();
    if (t == 0) {
        int r = 0;
        #pragma unroll
        for (int i = 0; i < 4; ++i) { woff[i] = r; r += wtot[i]; }
    }
    __syncthreads();
    int excl = sboff + woff[wv] + (s - ts);
    #pragma unroll
    for (int k = 0; k < 4; ++k) {
        const int idx = base + t * 4 + k;
        if (idx < N_NODES) { rowstart[idx] = excl; cursor[idx] = excl; }
        excl += c[k];
    }
}

// ---------------- K3: bucket edges into CSR order as 32B bf16 records ----
// record = 2 x uint4: {ea0..7 as 4x bf16-pair} , {ea8,9 pair, src, pad, pad}
// Line-aligned (2 records per 64B line), no straddle.
__global__ void k_scatter(const int* __restrict__ ei, const float* __restrict__ eattr,
                          int* __restrict__ cursor, uint4* __restrict__ csr_rec) {
    int e = blockIdx.x * blockDim.x + threadIdx.x;
    if (e < N_EDGES) {
        const int dst = ei[N_EDGES + e];
        const int src = ei[e];
        const float2* ea2 = (const float2*)(eattr + (size_t)e * ED);
        const float2 a0 = ea2[0], a1 = ea2[1], a2 = ea2[2], a3 = ea2[3], a4 = ea2[4];
        const int pos = atomicAdd(&cursor[dst], 1);
        uint4* o = csr_rec + (size_t)pos * 2;
        o[0] = make_uint4(packbf2(a0.x, a0.y), packbf2(a1.x, a1.y),
                          packbf2(a2.x, a2.y), packbf2(a3.x, a3.y));
        o[1] = make_uint4(packbf2(a4.x, a4.y), (uint)src, 0u, 0u);
    }
}

// ---------------- K_wprep: fused weight-prep + cnt-init (role-dispatched by blockIdx) ----
__global__ __launch_bounds__(256) void k_wprep(
    const float* __restrict__ Wee, const float* __restrict__ bee,
    const float* __restrict__ Wpre, const float* __restrict__ bpre,
    const float* __restrict__ Wpost, const float* __restrict__ bpost,
    const float* __restrict__ Wlin, const float* __restrict__ blin,
    float* __restrict__ W4, float* __restrict__ bp,
    ushort* __restrict__ WxT,     // [384][128]
    ushort* __restrict__ WaT,     // [384][512]
    float* __restrict__ b_comb,
    int* __restrict__ cnt)
{
    __shared__ float smem[128 * 128];   // 64 KB, aliased per role
    const int t = threadIdx.x;
    const int bx = blockIdx.x;

    if (bx < 104) {
        float* Wl = smem;
        for (int i = t; i < 128 * 128 / 4; i += 256)
            ((float4*)Wl)[i] = ((const float4*)Wlin)[i];
        __syncthreads();
        const int j = t & 127, rp = t >> 7;
        const int kr0 = bx * 16 + rp * 8;
        for (int r = 0; r < 8; ++r) {
            const int kr = kr0 + r;
            const float* wrow = Wpost + (size_t)kr * 128;
            float acc = 0.f;
            #pragma unroll 8
            for (int m = 0; m < 128; ++m) acc += wrow[m] * Wl[m * 128 + j];
            const ushort v = f2bf(acc);
            if (kr < 128)       WxT[(256 + j) * 128 + kr] = v;
            else if (kr < 640)  WaT[(size_t)j * 512 + (kr - 128)] = v;
            else if (kr < 1152) WaT[(size_t)(128 + j) * 512 + (kr - 640)] = v;
            else                WaT[(size_t)(256 + j) * 512 + (kr - 1152)] = v;
        }
        if (bx == 0 && t < 128) {
            float acc = 0.f;
            #pragma unroll 8
            for (int m = 0; m < 128; ++m) acc += bpost[m] * Wl[m * 128 + t];
            b_comb[t] = acc + blin[t];
        }
    } else if (bx == 104) {
        float* wee_s = smem;                 // ED*D
        float* bee_s = smem + ED * D;        // D
        for (int i = t; i < ED * D; i += 256) wee_s[i] = Wee[i];
        if (t < 128) bee_s[t] = bee[t];
        __syncthreads();
        if (t < 128) {
            float acc[ED];
            #pragma unroll
            for (int r = 0; r < ED; ++r) acc[r] = 0.f;
            float bacc = 0.f;
            for (int k = 0; k < D; ++k) {
                const float w3 = Wpre[(size_t)(2 * D + k) * D + t];
                #pragma unroll
                for (int r = 0; r < ED; ++r) acc[r] += wee_s[r * D + k] * w3;
                bacc += bee_s[k] * w3;
            }
            #pragma unroll
            for (int r = 0; r < ED; ++r) W4[r * D + t] = acc[r];
            bp[t] = bpre[t] + bacc;
        }
    } else if (bx < 121) {
        const int slice = (bx < 113) ? 0 : 1;
        const int id = (bx - (slice ? 113 : 105)) * 256 + t;   // 0..2047
        const float* src = Wpre + (size_t)slice * 128 * 128;
        ushort* dst = WxT + (size_t)slice * 128 * 128;
        const int col = id & 127;
        const int k0 = (id >> 7) * 8;
        ushort tmp[8];
        #pragma unroll
        for (int r = 0; r < 8; ++r) tmp[r] = f2bf(src[(size_t)(k0 + r) * 128 + col]);
        *(uint4*)(dst + (size_t)col * 128 + k0) = *(uint4*)tmp;
    } else {
        const int i = (bx - 121) * 256 + t;
        if (i < N_NODES) cnt[i] = 0;
    }
}

// ---------------- K_hx: fused hist + xgemm (both depend only on k_wprep) -------------
__global__ __launch_bounds__(256) void k_hx(
    const int* __restrict__ ei, int* __restrict__ cnt,
    const float* __restrict__ x, const ushort* __restrict__ WxT,
    const float* __restrict__ b_comb,
    ushort* __restrict__ Y1b, ushort* __restrict__ Y2b, float* __restrict__ out)
{
    const int t = threadIdx.x;
    if (blockIdx.x >= XGEMM_BLOCKS) {
        const int e = (blockIdx.x - XGEMM_BLOCKS) * 256 + t;
        if (e < N_EDGES) atomicAdd(&cnt[ei[N_EDGES + e]], 1);
        return;
    }

    __shared__ __align__(16) ushort Alds[128 * 136];
    __shared__ __align__(16) ushort Hlds[128 * 136];
    const int nb = blockIdx.x * 128;

    #pragma unroll
    for (int g = 0; g < 8; ++g) {
        const int idx = t + g * 256;
        const int row = idx >> 4, kk = (idx & 15) * 8;
        const int node = nb + row;
        uint4 v = make_uint4(0u, 0u, 0u, 0u);
        if (node < N_NODES) {
            const float4 f0 = *(const float4*)(x + (size_t)node * 128 + kk);
            const float4 f1 = *(const float4*)(x + (size_t)node * 128 + kk + 4);
            __hip_bfloat162 p0 = __float22bfloat162_rn(make_float2(f0.x, f0.y));
            __hip_bfloat162 p1 = __float22bfloat162_rn(make_float2(f0.z, f0.w));
            __hip_bfloat162 p2 = __float22bfloat162_rn(make_float2(f1.x, f1.y));
            __hip_bfloat162 p3 = __float22bfloat162_rn(make_float2(f1.z, f1.w));
            v.x = *(uint*)&p0; v.y = *(uint*)&p1; v.z = *(uint*)&p2; v.w = *(uint*)&p3;
        }
        *(uint4*)&Hlds[row * 136 + kk] = v;
    }

    const int w = t >> 6, l = t & 63;
    const int wr = w >> 1, wc = w & 1;
    const int quad = l >> 4, lr = l & 15;

    for (int sy = 0; sy < 3; ++sy) {
        __syncthreads();
        #pragma unroll
        for (int g = 0; g < 8; ++g) {
            const int idx = t + g * 256;
            const int row = idx >> 4, kk = (idx & 15) * 8;
            *(uint4*)&Alds[row * 136 + kk] =
                *(const uint4*)(WxT + ((size_t)sy * 128 + row) * 128 + kk);
        }
        __syncthreads();

        f32x4 acc[4][4];
        #pragma unroll
        for (int i = 0; i < 4; ++i)
            #pragma unroll
            for (int j = 0; j < 4; ++j) acc[i][j] = (f32x4){0.f, 0.f, 0.f, 0.f};

        #pragma unroll
        for (int s = 0; s < 4; ++s) {
            short8 av[4], bv[4];
            #pragma unroll
            for (int i = 0; i < 4; ++i)
                av[i] = *(const short8*)&Alds[(wr * 64 + i * 16 + lr) * 136 + s * 32 + quad * 8];
            #pragma unroll
            for (int j = 0; j < 4; ++j)
                bv[j] = *(const short8*)&Hlds[(wc * 64 + j * 16 + lr) * 136 + s * 32 + quad * 8];
            #pragma unroll
            for (int i = 0; i < 4; ++i)
                #pragma unroll
                for (int j = 0; j < 4; ++j)
                    acc[i][j] = __builtin_amdgcn_mfma_f32_16x16x32_bf16(av[i], bv[j], acc[i][j], 0, 0, 0);
        }

        #pragma unroll
        for (int i = 0; i < 4; ++i) {
            const int col = wr * 64 + i * 16 + quad * 4;
            #pragma unroll
            for (int j = 0; j < 4; ++j) {
                const int node = nb + wc * 64 + j * 16 + lr;
                if (node < N_NODES) {
                    const f32x4 v = acc[i][j];
                    if (sy == 2) {
                        *(float4*)(out + (size_t)node * 128 + col) =
                            make_float4(v.x + b_comb[col],     v.y + b_comb[col + 1],
                                        v.z + b_comb[col + 2], v.w + b_comb[col + 3]);
                    } else {
                        ushort* dst = (sy == 0) ? Y1b : Y2b;
                        ushort pk[4];
                        pk[0] = f2bf(v.x); pk[1] = f2bf(v.y);
                        pk[2] = f2bf(v.z); pk[3] = f2bf(v.w);
                        *(uint2*)(dst + (size_t)node * 128 + col) = *(uint2*)pk;
                    }
                }
            }
        }
    }
}

// ---------------- K8: CSR pull aggregation -> agg bf16 [N][512] ----------------
// Round-8 proven structure (scalar records + reg W4, no LDS); records now 32B bf16.
__global__ __launch_bounds__(256) void k_pull(
    const uint4* __restrict__ csr_rec, const float* __restrict__ W4,
    const float* __restrict__ bp, const ushort* __restrict__ Y1b,
    const ushort* __restrict__ Y2b,
    const int* __restrict__ rowstart,
    ushort* __restrict__ aggB)
{
    const int t = threadIdx.x;
    const int wv = t >> 6, l = t & 63;
    const int n = blockIdx.x * 4 + wv;

    // per-lane W4 slice (coalesced 512B/wave loads, L2-hot)
    float2 w4[ED];
    #pragma unroll
    for (int r = 0; r < ED; ++r)
        w4[r] = *(const float2*)(W4 + r * D + 2 * l);

    const int r0 = __builtin_amdgcn_readfirstlane(rowstart[n]);
    const int r1 = __builtin_amdgcn_readfirstlane(rowstart[n + 1]);
    const int d = r1 - r0;

    float s0 = 0.f, s1 = 0.f, ss0 = 0.f, ss1 = 0.f;
    float mx0 = -FLT_MAX, mx1 = -FLT_MAX, mn0 = FLT_MAX, mn1 = FLT_MAX;
    const __hip_bfloat162* Y2p = (const __hip_bfloat162*)Y2b;

    uint4 ra, rb;
    if (d > 0) {
        const uint4* rp = csr_rec + (size_t)r0 * 2;
        ra = rp[0]; rb = rp[1];
    }
    for (int i = r0; i < r1; ++i) {
        const int inext = (i + 1 < r1) ? (i + 1) : i;   // uniform, branchless clamp
        const uint4* rp = csr_rec + (size_t)inext * 2;
        const uint4 na = rp[0], nb4 = rp[1];

        const int src = (int)rb.y;                       // uniform -> scalar row base
        const float2 y2 = __bfloat1622float2(Y2p[(size_t)src * 64 + l]);

        // unpack 10 bf16 -> fp32 (uniform, scalar-pipe friendly: shift/and only)
        float ea[10];
        ea[0] = __uint_as_float(ra.x << 16); ea[1] = __uint_as_float(ra.x & 0xffff0000u);
        ea[2] = __uint_as_float(ra.y << 16); ea[3] = __uint_as_float(ra.y & 0xffff0000u);
        ea[4] = __uint_as_float(ra.z << 16); ea[5] = __uint_as_float(ra.z & 0xffff0000u);
        ea[6] = __uint_as_float(ra.w << 16); ea[7] = __uint_as_float(ra.w & 0xffff0000u);
        ea[8] = __uint_as_float(rb.x << 16); ea[9] = __uint_as_float(rb.x & 0xffff0000u);

        float q0 = 0.f, q1 = 0.f;
        #pragma unroll
        for (int r = 0; r < ED; ++r) {
            q0 += ea[r] * w4[r].x;
            q1 += ea[r] * w4[r].y;
        }
        const float z0 = y2.x + q0, z1 = y2.y + q1;
        s0 += z0; s1 += z1;
        ss0 += z0 * z0; ss1 += z1 * z1;
        mx0 = fmaxf(mx0, z0); mx1 = fmaxf(mx1, z1);
        mn0 = fminf(mn0, z0); mn1 = fminf(mn1, z1);

        ra = na; rb = nb4;
    }

    const float2 bpw = ((const float2*)bp)[l];
    const float2 y1 = __bfloat1622float2(((const __hip_bfloat162*)Y1b)[(size_t)n * 64 + l]);
    float mean0, mean1, vmx0, vmx1, vmn0, vmn1, st0, st1;
    if (d > 0) {
        const float inv = 1.f / (float)d;
        const float mz0 = s0 * inv, mz1 = s1 * inv;
        const float c0 = y1.x + bpw.x, c1 = y1.y + bpw.y;
        mean0 = mz0 + c0; mean1 = mz1 + c1;
        st0 = sqrtf(fmaxf(ss0 * inv - mz0 * mz0, 0.f) + EPS_PNA);
        st1 = sqrtf(fmaxf(ss1 * inv - mz1 * mz1, 0.f) + EPS_PNA);
        vmx0 = mx0 + c0; vmx1 = mx1 + c1;
        vmn0 = mn0 + c0; vmn1 = mn1 + c1;
    } else {
        mean0 = mean1 = 0.f;
        vmx0 = vmx1 = vmn0 = vmn1 = 0.f;
        st0 = st1 = sqrtf(EPS_PNA);
    }
    __hip_bfloat162* aggv = (__hip_bfloat162*)aggB;
    const size_t b0 = (size_t)n * 256;
    aggv[b0 + l]       = __float22bfloat162_rn(make_float2(mean0, mean1));
    aggv[b0 + 64 + l]  = __float22bfloat162_rn(make_float2(vmx0, vmx1));
    aggv[b0 + 128 + l] = __float22bfloat162_rn(make_float2(vmn0, vmn1));
    aggv[b0 + 192 + l] = __float22bfloat162_rn(make_float2(st0, st1));
}

// ---------------- K9: MFMA agg-GEMM v2 (round-7/8 proven) -------------------------
__global__ __launch_bounds__(256) void k_agg(
    const ushort* __restrict__ aggB,  // [N][512] bf16
    const ushort* __restrict__ WaT,   // [384][512] bf16
    const int* __restrict__ cnt, const float* __restrict__ avglog,
    float* __restrict__ out)
{
    __shared__ __align__(16) ushort Alds[3][128 * 72];   // 55.3 KB
    __shared__ __align__(16) ushort Hlds[64 * 72];       //  9.2 KB
    __shared__ float r1s[64], r2s[64];

    const int t = threadIdx.x;
    const int nb = blockIdx.x * 64;
    if (t < 64) {
        const int node = nb + t;
        float deg = 1.f;
        if (node < N_NODES) deg = fmaxf((float)cnt[node], 1.f);
        const float sl = logf(deg + 1.f);
        const float al = avglog[0];
        r1s[t] = sl / al;
        r2s[t] = al / sl;
    }

    const int w = t >> 6, l = t & 63;
    const int wr = w >> 1, wc = w & 1;   // wr: col half (64), wc: node half (32)
    const int quad = l >> 4, lr = l & 15;

    f32x4 acc[3][4][2];
    #pragma unroll
    for (int sl = 0; sl < 3; ++sl)
        #pragma unroll
        for (int i = 0; i < 4; ++i)
            #pragma unroll
            for (int j = 0; j < 2; ++j) acc[sl][i][j] = (f32x4){0.f, 0.f, 0.f, 0.f};

    for (int kc = 0; kc < 8; ++kc) {
        const int k0 = kc * 64;
        __syncthreads();                       // prior epoch's LDS reads done
        #pragma unroll
        for (int g = 0; g < 2; ++g) {          // H: 64 rows x 64 k
            const int idx = t + g * 256;
            const int row = idx >> 3, kk = (idx & 7) * 8;
            const int node = nb + row;
            uint4 v = make_uint4(0u, 0u, 0u, 0u);
            if (node < N_NODES)
                v = *(const uint4*)(aggB + (size_t)node * 512 + k0 + kk);
            *(uint4*)&Hlds[row * 72 + kk] = v;
        }
        #pragma unroll
        for (int sl = 0; sl < 3; ++sl) {       // A: 3 x (128 rows x 64 k)
            #pragma unroll
            for (int g = 0; g < 4; ++g) {
                const int idx = t + g * 256;
                const int row = idx >> 3, kk = (idx & 7) * 8;
                *(uint4*)&Alds[sl][row * 72 + kk] =
                    *(const uint4*)(WaT + ((size_t)(sl * 128 + row)) * 512 + k0 + kk);
            }
        }
        __syncthreads();                       // staged data visible
        #pragma unroll
        for (int sl = 0; sl < 3; ++sl) {
            #pragma unroll
            for (int s = 0; s < 2; ++s) {
                short8 av[4], bv[2];
                #pragma unroll
                for (int i = 0; i < 4; ++i)
                    av[i] = *(const short8*)&Alds[sl][(wr * 64 + i * 16 + lr) * 72 + s * 32 + quad * 8];
                #pragma unroll
                for (int j = 0; j < 2; ++j)
                    bv[j] = *(const short8*)&Hlds[(wc * 32 + j * 16 + lr) * 72 + s * 32 + quad * 8];
                #pragma unroll
                for (int i = 0; i < 4; ++i)
                    #pragma unroll
                    for (int j = 0; j < 2; ++j)
                        acc[sl][i][j] = __builtin_amdgcn_mfma_f32_16x16x32_bf16(av[i], bv[j], acc[sl][i][j], 0, 0, 0);
            }
        }
    }

    #pragma unroll
    for (int i = 0; i < 4; ++i) {
        const int col = wr * 64 + i * 16 + quad * 4;
        #pragma unroll
        for (int j = 0; j < 2; ++j) {
            const int node = nb + wc * 32 + j * 16 + lr;
            if (node < N_NODES) {
                const int nl = wc * 32 + j * 16 + lr;
                const float r1 = r1s[nl], r2 = r2s[nl];
                float* op = out + (size_t)node * 128 + col;
                const float4 cur = *(const float4*)op;
                const f32x4 a0 = acc[0][i][j];
                const f32x4 a1 = acc[1][i][j];
                const f32x4 a2 = acc[2][i][j];
                *(float4*)op = make_float4(
                    cur.x + a0.x + r1 * a1.x + r2 * a2.x,
                    cur.y + a0.y + r1 * a1.y + r2 * a2.y,
                    cur.z + a0.z + r1 * a1.z + r2 * a2.z,
                    cur.w + a0.w + r1 * a1.w + r2 * a2.w);
            }
        }
    }
}

extern "C" void kernel_launch(void* const* d_in, const int* in_sizes, int n_in,
                              void* d_out, int out_size, void* d_ws, size_t ws_size,
                              hipStream_t stream) {
    const float* x     = (const float*)d_in[0];
    const float* eattr = (const float*)d_in[1];
    const float* Wee   = (const float*)d_in[2];
    const float* bee   = (const float*)d_in[3];
    const float* Wpre  = (const float*)d_in[4];
    const float* bpre  = (const float*)d_in[5];
    const float* Wpost = (const float*)d_in[6];
    const float* bpost = (const float*)d_in[7];
    const float* Wlin  = (const float*)d_in[8];
    const float* blin  = (const float*)d_in[9];
    const int*   ei    = (const int*)d_in[10];
    float* out = (float*)d_out;

    // workspace layout (~94 MB; ws_size >= 102.6 MB proven previously)
    ushort* aggB = (ushort*)d_ws;                         // N*512 bf16 (51.2 MB)
    ushort* Y1b  = aggB + (size_t)N_NODES * 512;          // N*128 bf16 (12.8 MB)
    ushort* Y2b  = Y1b  + (size_t)N_NODES * 128;          // N*128 bf16 (12.8 MB)
    ushort* WxT  = Y2b  + (size_t)N_NODES * 128;          // 384*128 bf16
    ushort* WaT  = WxT + 384 * 128;                       // 384*512 bf16
    float*  W4   = (float*)(WaT + 384 * 512);             // ED*D fp32
    float*  bp   = W4 + ED * D;                           // 128
    float*  b_comb = bp + D;                              // 128
    float*  avglog = b_comb + D;                          // 1 (+3 pad)
    int*   cnt      = (int*)(avglog + 4);                 // 50000
    int*   rowstart = cnt + N_NODES;                      // 50001 (+3 pad)
    int*   cursor   = rowstart + N_NODES + 4;             // 50000
    uint4* csr_rec  = (uint4*)(cursor + N_NODES);         // E*32B (16.0 MB), 16B-aligned
    int*   bsum     = (int*)(csr_rec + (size_t)N_EDGES * 2);  // 49
    float* blog     = (float*)(bsum + 64);                // 49

    k_wprep<<<317, 256, 0, stream>>>(Wee, bee, Wpre, bpre, Wpost, bpost, Wlin, blin,
                                     W4, bp, WxT, WaT, b_comb, cnt);
    k_hx<<<XGEMM_BLOCKS + HIST_BLOCKS, 256, 0, stream>>>(ei, cnt, x, WxT, b_comb,
                                                         Y1b, Y2b, out);
    k_scanA<<<SCAN_NTILES, 256, 0, stream>>>(cnt, bsum, blog);
    k_scanC<<<SCAN_NTILES, 256, 0, stream>>>(cnt, bsum, blog, rowstart, cursor, avglog);
    k_scatter<<<(N_EDGES + 255) / 256, 256, 0, stream>>>(ei, eattr, cursor, csr_rec);
    k_pull<<<N_NODES / 4, 256, 0, stream>>>(csr_rec, W4, bp, Y1b, Y2b,
                                            rowstart, aggB);
    k_agg<<<(N_NODES + 63) / 64, 256, 0, stream>>>(aggB, WaT, cnt, avglog, out);
}